// Round 9
// baseline (246.432 us; speedup 1.0000x reference)
//
#include <hip/hip_runtime.h>
#include <hip/hip_bf16.h>
#include <math.h>

#define N_NODES 50000
#define N_EDGES 1600000
#define IN_FEAT 256
#define HIDDEN 128
#define N_CLASSES 16

#define ECHUNK 8192
#define NCHK 196    // ceil(1600000/8192)
#define NBKT 196    // ceil(50000/256) buckets of 256 nodes
#define BCAP 10240  // per-bucket capacity: mean 8192, +23 sigma
#define GEMM1_BLKS 782  // ceil(50000/64)

typedef __attribute__((ext_vector_type(8))) short short8;   // 8 bf16 (A/B frag)
typedef __attribute__((ext_vector_type(4))) float floatx4;  // C/D frag

__device__ __forceinline__ unsigned short f2bf(float f) {
    unsigned u = __float_as_uint(f);
    return (unsigned short)((u + 0x7fffu + ((u >> 16) & 1u)) >> 16);
}

__device__ __forceinline__ unsigned pk2bf(float a, float b) {
    __hip_bfloat162 h = __float22bfloat162_rn(make_float2(a, b));
    union { __hip_bfloat162 h; unsigned u; } cv;
    cv.h = h;
    return cv.u;
}

__device__ __forceinline__ float bflo(unsigned u) { return __uint_as_float(u << 16); }
__device__ __forceinline__ float bfhi(unsigned u) { return __uint_as_float(u & 0xffff0000u); }

// ---------------------------------------------------------------------------
// Prep A: chunk-local scatter into fixed-capacity dst buckets.
// Blocks 0..127 also transpose W1 -> bf16 w1t[n][k].
// ---------------------------------------------------------------------------
__global__ __launch_bounds__(256) void scatter_edges2(const int* __restrict__ src,
                                                      const int* __restrict__ dst,
                                                      int* __restrict__ cursor,   // [256], zeroed
                                                      unsigned int* __restrict__ sorted,
                                                      const float* __restrict__ W1,
                                                      unsigned short* __restrict__ w1t) {
    __shared__ int hloc[256];
    int t = threadIdx.x;
    hloc[t] = 0;
    if (blockIdx.x < HIDDEN)
        w1t[blockIdx.x * IN_FEAT + t] = f2bf(W1[t * HIDDEN + blockIdx.x]);
    __syncthreads();
    int base = blockIdx.x * ECHUNK;
    int end = min(base + ECHUNK, N_EDGES);
    for (int i = base + t; i < end; i += 256)
        atomicAdd(&hloc[dst[i] >> 8], 1);
    __syncthreads();
    int cnt = hloc[t];
    int lbase = t * BCAP + atomicAdd(&cursor[t], cnt);
    __syncthreads();
    hloc[t] = lbase;  // reuse as local cursor
    __syncthreads();
    for (int i = base + t; i < end; i += 256) {
        int d = dst[i];
        int s = src[i];
        int pos = atomicAdd(&hloc[d >> 8], 1);
        sorted[pos] = ((unsigned)d << 16) | (unsigned)s;
    }
}

// ---------------------------------------------------------------------------
// Prep B: per-node counts -> rs/re/dis (no fill; fill overlaps gemm1).
// ---------------------------------------------------------------------------
__global__ __launch_bounds__(256) void build_counts(const unsigned int* __restrict__ sorted,
                                                    const int* __restrict__ cursor,
                                                    int* __restrict__ rs,
                                                    int* __restrict__ re,
                                                    float* __restrict__ dis) {
    __shared__ int cnt[256];
    __shared__ int roff[256];
    int t = threadIdx.x;
    int bkt = blockIdx.x;
    int ebase = bkt * BCAP;
    int eend = ebase + cursor[bkt];
    cnt[t] = 0;
    __syncthreads();
    for (int i = ebase + t; i < eend; i += 256)
        atomicAdd(&cnt[(sorted[i] >> 16) & 255], 1);
    __syncthreads();
    int v = cnt[t];
    roff[t] = v;
    __syncthreads();
    for (int off = 1; off < 256; off <<= 1) {
        int x = (t >= off) ? roff[t - off] : 0;
        __syncthreads();
        roff[t] += x;
        __syncthreads();
    }
    int excl = roff[t] - v;
    int node = bkt * 256 + t;
    if (node < N_NODES) {
        rs[node] = ebase + excl;
        re[node] = ebase + excl + v;
        dis[node] = 1.0f / sqrtf((float)(v + 1));  // +1 self loop
    }
}

// ---------------------------------------------------------------------------
// Fused dispatch: blocks [0,NBKT) fill csr_src (cursors seeded from rs);
// blocks [NBKT, NBKT+GEMM1_BLKS) run the MFMA GEMM1. The 196-block fill
// hides under gemm1's 782 blocks on 256 CUs.
// ---------------------------------------------------------------------------
#define XCH 260   // dwords per 8-row LDS chunk: 8*32 + 4 pad

__global__ __launch_bounds__(256) void fill_and_gemm1(const unsigned int* __restrict__ sorted,
                                                      const int* __restrict__ cursor,
                                                      const int* __restrict__ rs,
                                                      unsigned short* __restrict__ csr_src,
                                                      const float* __restrict__ x,
                                                      const unsigned short* __restrict__ w1t,
                                                      const float* __restrict__ dis,
                                                      unsigned int* __restrict__ g1) {
    __shared__ float xs[2][8 * XCH];   // 16.6 KB (gemm); fill reuses as int[256]
    int tid = threadIdx.x;

    if (blockIdx.x < NBKT) {
        // ----- csr fill -----
        int* cnt = (int*)&xs[0][0];
        int t = tid;
        int bkt = blockIdx.x;
        int ebase = bkt * BCAP;
        int eend = ebase + cursor[bkt];
        int node = bkt * 256 + t;
        cnt[t] = (node < N_NODES) ? rs[node] : 0;
        __syncthreads();
        for (int i = ebase + t; i < eend; i += 256) {
            unsigned e = sorted[i];
            int pos = atomicAdd(&cnt[(e >> 16) & 255], 1);
            csr_src[pos] = (unsigned short)(e & 0xffffu);
        }
        return;
    }

    // ----- gemm1 -----
    int bid = blockIdx.x - NBKT;
    int w = tid >> 6;
    int lane = tid & 63;
    int quad = lane >> 4;
    int c = lane & 15;
    int row_base = bid * 64;
    int wrow = (w >> 1) * 32;
    int col_base = (w & 1) * 64;

    int st_row = min(row_base + 16 * w + (lane >> 3), N_NODES - 1);
    int st_row2 = min(row_base + 16 * w + 8 + (lane >> 3), N_NODES - 1);
    const float* gp1 = x + (size_t)st_row * IN_FEAT + (lane & 7) * 4;
    const float* gp2 = x + (size_t)st_row2 * IN_FEAT + (lane & 7) * 4;

    floatx4 acc[2][4] = {};
    const unsigned short* bp[4];
#pragma unroll
    for (int nt = 0; nt < 4; ++nt)
        bp[nt] = w1t + (size_t)(col_base + nt * 16 + c) * IN_FEAT + quad * 8;

    int dwoff[2];
#pragma unroll
    for (int rt = 0; rt < 2; ++rt) {
        int rit = wrow + rt * 16 + c;
        dwoff[rt] = (rit >> 3) * XCH + (rit & 7) * 32 + quad * 8;
    }

#define STAGE(buf, k0)                                                                  \
    do {                                                                                \
        __builtin_amdgcn_global_load_lds(                                               \
            (const __attribute__((address_space(1))) void*)(gp1 + (k0)),                \
            (__attribute__((address_space(3))) void*)&xs[buf][(2 * w) * XCH], 16, 0, 0);\
        __builtin_amdgcn_global_load_lds(                                               \
            (const __attribute__((address_space(1))) void*)(gp2 + (k0)),                \
            (__attribute__((address_space(3))) void*)&xs[buf][(2 * w + 1) * XCH], 16, 0, 0);\
    } while (0)

    STAGE(0, 0);
    __syncthreads();

    int buf = 0;
#pragma unroll
    for (int kk = 0; kk < 8; ++kk) {
        if (kk < 7) STAGE(buf ^ 1, (kk + 1) * 32);
        short8 b[4];
#pragma unroll
        for (int nt = 0; nt < 4; ++nt)
            b[nt] = *(const short8*)(bp[nt] + kk * 32);
        short8 a[2];
#pragma unroll
        for (int rt = 0; rt < 2; ++rt) {
            float4 f0 = *(const float4*)&xs[buf][dwoff[rt]];
            float4 f1 = *(const float4*)&xs[buf][dwoff[rt] + 4];
            union { short8 s; unsigned u[4]; } au;
            au.u[0] = pk2bf(f0.x, f0.y);
            au.u[1] = pk2bf(f0.z, f0.w);
            au.u[2] = pk2bf(f1.x, f1.y);
            au.u[3] = pk2bf(f1.z, f1.w);
            a[rt] = au.s;
        }
#pragma unroll
        for (int rt = 0; rt < 2; ++rt)
#pragma unroll
            for (int nt = 0; nt < 4; ++nt)
                acc[rt][nt] = __builtin_amdgcn_mfma_f32_16x16x32_bf16(a[rt], b[nt], acc[rt][nt], 0, 0, 0);
        __syncthreads();
        buf ^= 1;
    }
#undef STAGE

    bool evenlane = (lane & 1) == 0;
#pragma unroll
    for (int rt = 0; rt < 2; ++rt) {
#pragma unroll
        for (int reg = 0; reg < 4; ++reg) {
            int row = row_base + wrow + rt * 16 + quad * 4 + reg;
            float dv = dis[min(row, N_NODES - 1)];
#pragma unroll
            for (int nt = 0; nt < 4; ++nt) {
                float v = acc[rt][nt][reg] * dv;
                float vo = __shfl_xor(v, 1);
                if (evenlane && row < N_NODES) {
                    unsigned pkd = (unsigned)f2bf(v) | ((unsigned)f2bf(vo) << 16);
                    g1[(size_t)row * 64 + (col_base >> 1) + nt * 8 + (c >> 1)] = pkd;
                }
            }
        }
    }
}

// ---------------------------------------------------------------------------
// Fused: aggregation 1 + bias + ReLU + GEMM2 (+dis scale).
// Half-wave pair gather: 32 lanes x dwordx2 per row, unroll 8 pairs.
// ---------------------------------------------------------------------------
__global__ __launch_bounds__(256) void agg1_gemm2(const unsigned int* __restrict__ g1,
                                                  const int* __restrict__ rs,
                                                  const int* __restrict__ re,
                                                  const unsigned short* __restrict__ csr_src,
                                                  const float* __restrict__ dis,
                                                  const float* __restrict__ b1,
                                                  const float* __restrict__ W2,
                                                  float* __restrict__ g2) {
    __shared__ float w2s[HIDDEN * N_CLASSES];   // 8 KB
    __shared__ float rsh[4][HIDDEN];            // 2 KB, per-wave regions
    int tid = threadIdx.x;
    for (int i = tid; i < HIDDEN * N_CLASSES; i += 256) w2s[i] = W2[i];
    __syncthreads();

    int wave = tid >> 6;
    int lane = tid & 63;
    int hi = lane >> 5;
    int m = lane & 31;
    int node = blockIdx.x * 4 + wave;
    const uint2* g = (const uint2*)g1;

    float s0 = 0.f, s1 = 0.f, s2 = 0.f, s3 = 0.f;
    float t0 = 0.f, t1 = 0.f, t2 = 0.f, t3 = 0.f;
    if (hi == 0) {
        uint2 su = g[(size_t)node * 32 + m];
        s0 = bflo(su.x); s1 = bfhi(su.x); s2 = bflo(su.y); s3 = bfhi(su.y);
    }

    int e0 = rs[node], e1 = re[node];
    int e = e0;
    for (; e + 16 <= e1; e += 16) {
        int i0 = csr_src[e + 0 + hi], i1 = csr_src[e + 2 + hi];
        int i2 = csr_src[e + 4 + hi], i3 = csr_src[e + 6 + hi];
        int i4 = csr_src[e + 8 + hi], i5 = csr_src[e + 10 + hi];
        int i6 = csr_src[e + 12 + hi], i7 = csr_src[e + 14 + hi];
        uint2 u0 = g[(size_t)i0 * 32 + m];
        uint2 u1 = g[(size_t)i1 * 32 + m];
        uint2 u2 = g[(size_t)i2 * 32 + m];
        uint2 u3 = g[(size_t)i3 * 32 + m];
        uint2 u4 = g[(size_t)i4 * 32 + m];
        uint2 u5 = g[(size_t)i5 * 32 + m];
        uint2 u6 = g[(size_t)i6 * 32 + m];
        uint2 u7 = g[(size_t)i7 * 32 + m];
        s0 += bflo(u0.x); s1 += bfhi(u0.x); s2 += bflo(u0.y); s3 += bfhi(u0.y);
        t0 += bflo(u1.x); t1 += bfhi(u1.x); t2 += bflo(u1.y); t3 += bfhi(u1.y);
        s0 += bflo(u2.x); s1 += bfhi(u2.x); s2 += bflo(u2.y); s3 += bfhi(u2.y);
        t0 += bflo(u3.x); t1 += bfhi(u3.x); t2 += bflo(u3.y); t3 += bfhi(u3.y);
        s0 += bflo(u4.x); s1 += bfhi(u4.x); s2 += bflo(u4.y); s3 += bfhi(u4.y);
        t0 += bflo(u5.x); t1 += bfhi(u5.x); t2 += bflo(u5.y); t3 += bfhi(u5.y);
        s0 += bflo(u6.x); s1 += bfhi(u6.x); s2 += bflo(u6.y); s3 += bfhi(u6.y);
        t0 += bflo(u7.x); t1 += bfhi(u7.x); t2 += bflo(u7.y); t3 += bfhi(u7.y);
    }
    for (; e + 2 <= e1; e += 2) {
        int i0 = csr_src[e + hi];
        uint2 u = g[(size_t)i0 * 32 + m];
        s0 += bflo(u.x); s1 += bfhi(u.x); s2 += bflo(u.y); s3 += bfhi(u.y);
    }
    if (e < e1 && hi == 0) {
        int i0 = csr_src[e];
        uint2 u = g[(size_t)i0 * 32 + m];
        s0 += bflo(u.x); s1 += bfhi(u.x); s2 += bflo(u.y); s3 += bfhi(u.y);
    }
    s0 += t0; s1 += t1; s2 += t2; s3 += t3;
    s0 += __shfl_xor(s0, 32);
    s1 += __shfl_xor(s1, 32);
    s2 += __shfl_xor(s2, 32);
    s3 += __shfl_xor(s3, 32);

    float dv = dis[node];
    if (hi == 0) {
        float4 bb = *(const float4*)&b1[4 * m];
        float4 r;
        r.x = fmaxf(fmaf(dv, s0, bb.x), 0.f);
        r.y = fmaxf(fmaf(dv, s1, bb.y), 0.f);
        r.z = fmaxf(fmaf(dv, s2, bb.z), 0.f);
        r.w = fmaxf(fmaf(dv, s3, bb.w), 0.f);
        *(float4*)&rsh[wave][4 * m] = r;
    }

    int grp = lane >> 4;
    int c = lane & 15;
    int f0 = grp * 32;
    float p = 0.f;
#pragma unroll
    for (int k = 0; k < 32; ++k)
        p = fmaf(rsh[wave][f0 + k], w2s[(f0 + k) * N_CLASSES + c], p);
    p += __shfl_xor(p, 16);
    p += __shfl_xor(p, 32);
    if (lane < 16) g2[(size_t)node * N_CLASSES + lane] = dv * p;
}

// ---------------------------------------------------------------------------
// Aggregation 2 + bias + logits + softmax. One WAVE per node:
// 4 edge-groups (grp=lane>>4) x 8-unroll = 32 edges in flight per wave,
// cross-group combine via shfl_xor(16/32).
// ---------------------------------------------------------------------------
__global__ __launch_bounds__(256) void agg2_softmax(const float* __restrict__ g2,
                                                    const int* __restrict__ rs,
                                                    const int* __restrict__ re,
                                                    const unsigned short* __restrict__ csr_src,
                                                    const float* __restrict__ dis,
                                                    const float* __restrict__ b2,
                                                    float* __restrict__ out) {
    int tid = threadIdx.x;
    int wave = tid >> 6;
    int lane = tid & 63;
    int grp = lane >> 4;
    int c = lane & 15;
    int node = blockIdx.x * 4 + wave;  // 12500*4 == 50000

    float acc0 = (grp == 0) ? g2[(size_t)node * N_CLASSES + c] : 0.f;  // self loop
    float acc1 = 0.f, acc2 = 0.f, acc3 = 0.f;
    float acc4 = 0.f, acc5 = 0.f, acc6 = 0.f, acc7 = 0.f;
    int e0 = rs[node], e1 = re[node];
    int e = e0;
    for (; e + 32 <= e1; e += 32) {
        int i0 = csr_src[e + grp], i1 = csr_src[e + 4 + grp];
        int i2 = csr_src[e + 8 + grp], i3 = csr_src[e + 12 + grp];
        int i4 = csr_src[e + 16 + grp], i5 = csr_src[e + 20 + grp];
        int i6 = csr_src[e + 24 + grp], i7 = csr_src[e + 28 + grp];
        acc0 += g2[(size_t)i0 * N_CLASSES + c];
        acc1 += g2[(size_t)i1 * N_CLASSES + c];
        acc2 += g2[(size_t)i2 * N_CLASSES + c];
        acc3 += g2[(size_t)i3 * N_CLASSES + c];
        acc4 += g2[(size_t)i4 * N_CLASSES + c];
        acc5 += g2[(size_t)i5 * N_CLASSES + c];
        acc6 += g2[(size_t)i6 * N_CLASSES + c];
        acc7 += g2[(size_t)i7 * N_CLASSES + c];
    }
    for (; e + 4 <= e1; e += 4) {
        int i = csr_src[e + grp];
        acc1 += g2[(size_t)i * N_CLASSES + c];
    }
    if (e + grp < e1) {
        int i = csr_src[e + grp];
        acc2 += g2[(size_t)i * N_CLASSES + c];
    }
    float sum = ((acc0 + acc1) + (acc2 + acc3)) + ((acc4 + acc5) + (acc6 + acc7));
    sum += __shfl_xor(sum, 16);
    sum += __shfl_xor(sum, 32);

    float logit = fmaf(dis[node], sum, b2[c]);
    if (lane < 16) out[(size_t)node * N_CLASSES + c] = logit;
    float m = logit;
    for (int off = 8; off; off >>= 1) m = fmaxf(m, __shfl_xor(m, off));
    float ex = expf(logit - m);
    float s = ex;
    for (int off = 8; off; off >>= 1) s += __shfl_xor(s, off);
    if (lane < 16) out[(size_t)N_NODES * N_CLASSES + (size_t)node * N_CLASSES + c] = ex / s;
}

// ---------------------------------------------------------------------------

extern "C" void kernel_launch(void* const* d_in, const int* in_sizes, int n_in,
                              void* d_out, int out_size, void* d_ws, size_t ws_size,
                              hipStream_t stream) {
    const float* x  = (const float*)d_in[0];
    const int*   ei = (const int*)d_in[1];
    const float* W1 = (const float*)d_in[2];
    const float* b1 = (const float*)d_in[3];
    const float* W2 = (const float*)d_in[4];
    const float* b2 = (const float*)d_in[5];
    float* out = (float*)d_out;

    char* ws = (char*)d_ws;
    size_t off = 0;
    auto alloc = [&](size_t bytes) -> char* {
        char* p = ws + off;
        off = (off + bytes + 511) & ~(size_t)511;
        return p;
    };
    int*   cursor   = (int*)alloc(256 * 4);
    float* dis      = (float*)alloc(N_NODES * 4);
    int*   rs       = (int*)alloc(N_NODES * 4);
    int*   re       = (int*)alloc(N_NODES * 4);
    unsigned short* w1t = (unsigned short*)alloc((size_t)HIDDEN * IN_FEAT * 2);
    unsigned short* csr_src = (unsigned short*)alloc((size_t)NBKT * BCAP * 2);  // holey
    unsigned int* sorted = (unsigned int*)alloc((size_t)NBKT * BCAP * 4);       // own slab:
    // fill reads sorted while gemm1 writes g1 in the same dispatch -> no alias.
    unsigned int* g1 = (unsigned int*)alloc((size_t)N_NODES * 64 * 4);          // bf16x2/lane
    float* g2       = (float*)alloc((size_t)N_NODES * N_CLASSES * 4);
    (void)ws_size; (void)in_sizes; (void)n_in; (void)out_size;

    const int* src = ei;
    const int* dst = ei + N_EDGES;

    hipMemsetAsync(cursor, 0, 256 * 4, stream);
    scatter_edges2<<<NCHK, 256, 0, stream>>>(src, dst, cursor, sorted, W1, w1t);
    build_counts<<<NBKT, 256, 0, stream>>>(sorted, cursor, rs, re, dis);
    fill_and_gemm1<<<NBKT + GEMM1_BLKS, 256, 0, stream>>>(sorted, cursor, rs, csr_src,
                                                          x, w1t, dis, g1);
    agg1_gemm2<<<N_NODES / 4, 256, 0, stream>>>(g1, rs, re, csr_src, dis, b1, W2, g2);
    agg2_softmax<<<N_NODES / 4, 256, 0, stream>>>(g2, rs, re, csr_src, dis, b2, out);
}